// Round 11
// baseline (961.378 us; speedup 1.0000x reference)
//
#include <hip/hip_runtime.h>

// MAF forward: 32 autoregressive MADE steps, fully fused. N=65536, D=32, H=1024, C=64.
// R10 = R6 (register-chained GEMM1->tanh->GEMM2, W2 k-permuted, per-wave-slice
//   partials + read-reduce, 2 barriers/step, 1 blk/CU) with Ppw stored as
//   u32-PACKED bf16 pairs (samples 2k,2k+1 same col in one word):
//   - pack via manual RNE bit-twiddle (NO inline asm on MFMA acc)
//   - plain ds_write_b32 / ds_read_b32 (NO 16-bit LDS ops)
//   Isolates bf16-partials from the two code paths suspected in R8/R9's NaN.
// ws layout (bf16 as u16):
//   [0      .. 32768)  W1mT  [h=1024][d=32]   = W1[d][h]*mask1 * 2log2e
//   [32768  .. 98304)  W2mTp [c=64][q=1024]   = W2[perm(q)][c]*mask2
//   [98304  ..163840)  WcT   [h=1024][c=64]   = Wc[c][h] * 2log2e

#define NS 65536
#define HH 1024
#define K2LOG2E 2.885390082f

typedef __attribute__((ext_vector_type(8))) short short8;
typedef __attribute__((ext_vector_type(4))) float f32x4;

__device__ inline unsigned short f2bf(float f) {
  unsigned int u = __builtin_bit_cast(unsigned int, f);
  u += 0x7fffu + ((u >> 16) & 1u);          // RNE
  return (unsigned short)(u >> 16);
}
__device__ inline unsigned int pack2bf(float a, float b) {
  return (unsigned int)f2bf(a) | ((unsigned int)f2bf(b) << 16);
}
__device__ inline unsigned int cvt_pk_bf16(float lo, float hi) {
  unsigned int r;
  asm("v_cvt_pk_bf16_f32 %0, %1, %2" : "=v"(r) : "v"(lo), "v"(hi));
  return r;
}
__device__ inline float bflo(unsigned int p) { return __builtin_bit_cast(float, p << 16); }
__device__ inline float bfhi(unsigned int p) { return __builtin_bit_cast(float, p & 0xffff0000u); }
// input pre-scaled by 2log2e: tanh = 1 - 2/(1+exp2(z)); saturates for |z| large
__device__ inline float tanh_pre(float z) {
  float t = __builtin_amdgcn_exp2f(z);
  float r = __builtin_amdgcn_rcpf(t + 1.0f);
  return fmaf(-2.0f, r, 1.0f);
}

__global__ void maf_prep(const float* __restrict__ W1, const float* __restrict__ Wc,
                         const float* __restrict__ W2, unsigned short* __restrict__ ws) {
  int t = blockIdx.x * blockDim.x + threadIdx.x;     // 0 .. 163839
  if (t < 32768) {                                   // W1mT [h][d], scaled
    int h = t >> 5, d = t & 31;
    int deg = h % 31 + 1;                            // hid_deg
    float v = (deg >= d + 1) ? W1[(size_t)d * HH + h] * K2LOG2E : 0.f;
    ws[t] = f2bf(v);
  } else if (t < 98304) {                            // W2mTp [c][q], k-permuted
    int i = t - 32768;
    int c = i >> 10, q = i & 1023;
    int wv = q >> 6, m = (q >> 5) & 1, lk = (q >> 3) & 3, jp = (q >> 2) & 1, r = q & 3;
    int h = wv * 64 + (2 * m + jp) * 16 + 4 * lk + r;
    int deg = h % 31 + 1;
    float v = (((c >> 1) + 1) > deg) ? W2[(size_t)h * 64 + c] : 0.f;
    ws[t] = f2bf(v);
  } else {                                           // WcT [h][c], scaled
    int i = t - 98304;
    int h = i >> 6, c = i & 63;
    ws[t] = f2bf(Wc[(size_t)c * HH + h] * K2LOG2E);
  }
}

__global__ __launch_bounds__(1024, 4) void maf_main(
    const float* __restrict__ x, const float* __restrict__ ctx,
    const float* __restrict__ b1, const float* __restrict__ b2,
    const unsigned short* __restrict__ ws, float* __restrict__ out)
{
  // LDS: 2560 + 69632 = 72192 B (1 block/CU; 4 waves/EU => 128-reg cap)
  __shared__ __align__(16) unsigned short ybf[32][40];     // y bf16 [s][d]
  __shared__ __align__(16) unsigned int Ppw32[16][16][68]; // per-wave P partials,
                                                           // u32 = bf16{s=2k,s=2k+1}

  const unsigned short* W1mT  = ws;            // [1024][32]
  const unsigned short* W2mTp = ws + 32768;    // [64][1024] (k-permuted)
  const unsigned short* WcT   = ws + 98304;    // [1024][64]

  const int tid  = threadIdx.x;
  const int lane = tid & 63;
  const int w    = tid >> 6;        // wave 0..15: owns h-chunk [64w, 64w+64)
  const int l15  = lane & 15;
  const int lk   = lane >> 4;       // 0..3
  const int s0   = blockIdx.x * 32;

  // zero y (as R6)
  if (tid < 640) reinterpret_cast<unsigned int*>(&ybf[0][0])[tid] = 0u;

  // ---- ctx B-fragments from global (f32 -> bf16 via cvt_pk; R6-validated) ----
  short8 cf[2][2];
#pragma unroll
  for (int sh = 0; sh < 2; ++sh)
#pragma unroll
    for (int kc = 0; kc < 2; ++kc) {
      const float* cp = ctx + (size_t)(s0 + sh * 16 + l15) * 64 + kc * 32 + lk * 8;
      f32x4 a = *reinterpret_cast<const f32x4*>(cp);
      f32x4 b = *reinterpret_cast<const f32x4*>(cp + 4);
      union { short8 s; unsigned int u[4]; } t;
      t.u[0] = cvt_pk_bf16(a[0], a[1]);
      t.u[1] = cvt_pk_bf16(a[2], a[3]);
      t.u[2] = cvt_pk_bf16(b[0], b[1]);
      t.u[3] = cvt_pk_bf16(b[2], b[3]);
      cf[sh][kc] = t.s;
    }

  // ---- WcH^T + b1 (both pre-scaled) for this wave's 64 h-rows; f32 (32 regs) ----
  f32x4 wch[2][4];
#pragma unroll
  for (int j = 0; j < 4; ++j) {
    int h0 = w * 64 + j * 16;
    f32x4 binit = *reinterpret_cast<const f32x4*>(b1 + h0 + 4 * lk);
    binit *= K2LOG2E;
#pragma unroll
    for (int sh = 0; sh < 2; ++sh) {
      f32x4 acc = binit;
#pragma unroll
      for (int kc = 0; kc < 2; ++kc) {
        short8 af = *reinterpret_cast<const short8*>(WcT + (size_t)(h0 + l15) * 64 + kc * 32 + lk * 8);
        acc = __builtin_amdgcn_mfma_f32_16x16x32_bf16(af, cf[sh][kc], acc, 0, 0, 0);
      }
      wch[sh][j] = acc;
    }
  }

  // ---- W1 A-fragments, register-resident (16 regs) ----
  short8 w1f[4];
#pragma unroll
  for (int j = 0; j < 4; ++j)
    w1f[j] = *reinterpret_cast<const short8*>(W1mT + (size_t)(w * 64 + j * 16 + l15) * 32 + lk * 8);

  // ---- W2 B-fragments for own h-chunk, all 64 c (32 regs): w2f[ct][m] ----
  short8 w2f[4][2];
#pragma unroll
  for (int ct = 0; ct < 4; ++ct)
#pragma unroll
    for (int m = 0; m < 2; ++m)
      w2f[ct][m] = *reinterpret_cast<const short8*>(
          W2mTp + (size_t)(16 * ct + l15) * 1024 + w * 64 + m * 32 + lk * 8);

  // ---- epilogue role: thread -> (sample se, dim de) ----
  const int se = tid >> 5, de = tid & 31;
  const int wr = se >> 1, half = se & 1;    // word row / halfword within Ppw32
  const float xv  = x[(size_t)(s0 + se) * 32 + de];
  const float b2e = b2[2 * de], b2o = b2[2 * de + 1];
  float ls_last = 0.f;

  __syncthreads();

#pragma unroll 1
  for (int step = 0; step < 32; ++step) {
    // ---- GEMM1 + tanh, all in registers; pa[sh][j] = packed bf16 hid frags ----
    short8 yb0 = *reinterpret_cast<const short8*>(&ybf[l15][lk * 8]);
    short8 yb1 = *reinterpret_cast<const short8*>(&ybf[16 + l15][lk * 8]);
    unsigned int pa[2][4][2];
#pragma unroll
    for (int j = 0; j < 4; ++j) {
      f32x4 c0 = __builtin_amdgcn_mfma_f32_16x16x32_bf16(w1f[j], yb0, wch[0][j], 0, 0, 0);
      f32x4 c1 = __builtin_amdgcn_mfma_f32_16x16x32_bf16(w1f[j], yb1, wch[1][j], 0, 0, 0);
      pa[0][j][0] = cvt_pk_bf16(tanh_pre(c0[0]), tanh_pre(c0[1]));
      pa[0][j][1] = cvt_pk_bf16(tanh_pre(c0[2]), tanh_pre(c0[3]));
      pa[1][j][0] = cvt_pk_bf16(tanh_pre(c1[0]), tanh_pre(c1[1]));
      pa[1][j][1] = cvt_pk_bf16(tanh_pre(c1[2]), tanh_pre(c1[3]));
    }

    // ---- GEMM2 over own h-chunk from registers; packed-u32 partials to own slice ----
#pragma unroll
    for (int ct = 0; ct < 4; ++ct) {
#pragma unroll
      for (int sh = 0; sh < 2; ++sh) {
        union { unsigned int u[4]; short8 s; } a0, a1;
        a0.u[0] = pa[sh][0][0]; a0.u[1] = pa[sh][0][1];
        a0.u[2] = pa[sh][1][0]; a0.u[3] = pa[sh][1][1];
        a1.u[0] = pa[sh][2][0]; a1.u[1] = pa[sh][2][1];
        a1.u[2] = pa[sh][3][0]; a1.u[3] = pa[sh][3][1];
        f32x4 acc = {0.f, 0.f, 0.f, 0.f};
        acc = __builtin_amdgcn_mfma_f32_16x16x32_bf16(a0.s, w2f[ct][0], acc, 0, 0, 0);
        acc = __builtin_amdgcn_mfma_f32_16x16x32_bf16(a1.s, w2f[ct][1], acc, 0, 0, 0);
        // rows (samples) 16sh+4lk+{0,1} -> word row 8sh+2lk; {2,3} -> +1
        Ppw32[w][8 * sh + 2 * lk + 0][16 * ct + l15] = pack2bf(acc[0], acc[1]);
        Ppw32[w][8 * sh + 2 * lk + 1][16 * ct + l15] = pack2bf(acc[2], acc[3]);
      }
    }
    __syncthreads();

    // ---- epilogue: thread (se,de): reduce 16 packed slices, y = x*exp(ls)+sh ----
    {
      float shv = b2e, lsv = b2o;
#pragma unroll
      for (int q = 0; q < 16; ++q) {
        unsigned int v0 = Ppw32[q][wr][2 * de];
        unsigned int v1 = Ppw32[q][wr][2 * de + 1];
        shv += half ? bfhi(v0) : bflo(v0);
        lsv += half ? bfhi(v1) : bflo(v1);
      }
      float yv = fmaf(xv, __expf(lsv), shv);
      ybf[se][de] = f2bf(yv);
      if (step == 31) {
        out[(size_t)(s0 + se) * 32 + de] = yv;
        ls_last = lsv;
      }
    }
    __syncthreads();
  }

  // ---- log_det: reduce ls over de within each 32-lane group ----
  float v = ls_last;
  v += __shfl_xor(v, 1);
  v += __shfl_xor(v, 2);
  v += __shfl_xor(v, 4);
  v += __shfl_xor(v, 8);
  v += __shfl_xor(v, 16);
  if (de == 0) out[(size_t)NS * 32 + s0 + se] = v;
}

extern "C" void kernel_launch(void* const* d_in, const int* in_sizes, int n_in,
                              void* d_out, int out_size, void* d_ws, size_t ws_size,
                              hipStream_t stream) {
  (void)in_sizes; (void)n_in; (void)out_size; (void)ws_size;
  const float* x   = (const float*)d_in[0];
  const float* ctx = (const float*)d_in[1];
  const float* W1  = (const float*)d_in[2];
  const float* b1  = (const float*)d_in[3];
  const float* Wc  = (const float*)d_in[4];
  const float* W2  = (const float*)d_in[5];
  const float* b2  = (const float*)d_in[6];
  unsigned short* ws = (unsigned short*)d_ws;
  float* out = (float*)d_out;

  maf_prep<<<640, 256, 0, stream>>>(W1, Wc, W2, ws);
  maf_main<<<2048, 1024, 0, stream>>>(x, ctx, b1, b2, ws, out);
}

// Round 12
// 751.408 us; speedup vs baseline: 1.2794x; 1.2794x over previous
//
#include <hip/hip_runtime.h>

// MAF forward: 32 autoregressive MADE steps, fully fused. N=65536, D=32, H=1024, C=64.
// R11 = R6 (register-chained GEMM1->tanh->GEMM2, W2 k-permuted, f32 per-wave-slice
//   partials + read-reduce, 2 barriers/step, 1 blk/CU, 874us) + VALU/latency cuts:
//   (1) epilogue: f32x2 tree reduce (v_pk_add_f32, depth 4) instead of 16-deep
//       scalar chain; (2) log-scale columns pre-scaled by log2e in prep ->
//       epilogue uses exp2 directly (ls un-scaled once at step 31);
//   (3) GEMM2 restructured sh-outer so A-fragments are built once per sh.
// ws layout (bf16 as u16):
//   [0      .. 32768)  W1mT  [h=1024][d=32]   = W1[d][h]*mask1 * 2log2e
//   [32768  .. 98304)  W2mTp [c=64][q=1024]   = W2[perm(q)][c]*mask2 * (c odd ? log2e : 1)
//   [98304  ..163840)  WcT   [h=1024][c=64]   = Wc[c][h] * 2log2e

#define NS 65536
#define HH 1024
#define K2LOG2E 2.885390082f
#define KLOG2E 1.4426950408889634f
#define KLN2 0.6931471805599453f

typedef __attribute__((ext_vector_type(8))) short short8;
typedef __attribute__((ext_vector_type(4))) float f32x4;
typedef __attribute__((ext_vector_type(2))) float f32x2;

__device__ inline unsigned short f2bf(float f) {
  unsigned int u = __builtin_bit_cast(unsigned int, f);
  u += 0x7fffu + ((u >> 16) & 1u);          // RNE
  return (unsigned short)(u >> 16);
}
__device__ inline unsigned int cvt_pk_bf16(float lo, float hi) {
  unsigned int r;
  asm("v_cvt_pk_bf16_f32 %0, %1, %2" : "=v"(r) : "v"(lo), "v"(hi));
  return r;
}
// input pre-scaled by 2log2e: tanh = 1 - 2/(1+exp2(z)); saturates for |z| large
__device__ inline float tanh_pre(float z) {
  float t = __builtin_amdgcn_exp2f(z);
  float r = __builtin_amdgcn_rcpf(t + 1.0f);
  return fmaf(-2.0f, r, 1.0f);
}

__global__ void maf_prep(const float* __restrict__ W1, const float* __restrict__ Wc,
                         const float* __restrict__ W2, unsigned short* __restrict__ ws) {
  int t = blockIdx.x * blockDim.x + threadIdx.x;     // 0 .. 163839
  if (t < 32768) {                                   // W1mT [h][d], scaled
    int h = t >> 5, d = t & 31;
    int deg = h % 31 + 1;                            // hid_deg
    float v = (deg >= d + 1) ? W1[(size_t)d * HH + h] * K2LOG2E : 0.f;
    ws[t] = f2bf(v);
  } else if (t < 98304) {                            // W2mTp [c][q], k-permuted
    int i = t - 32768;
    int c = i >> 10, q = i & 1023;
    int wv = q >> 6, m = (q >> 5) & 1, lk = (q >> 3) & 3, jp = (q >> 2) & 1, r = q & 3;
    int h = wv * 64 + (2 * m + jp) * 16 + 4 * lk + r;
    int deg = h % 31 + 1;
    float v = (((c >> 1) + 1) > deg) ? W2[(size_t)h * 64 + c] : 0.f;
    if (c & 1) v *= KLOG2E;                          // log-scale cols in log2 domain
    ws[t] = f2bf(v);
  } else {                                           // WcT [h][c], scaled
    int i = t - 98304;
    int h = i >> 6, c = i & 63;
    ws[t] = f2bf(Wc[(size_t)c * HH + h] * K2LOG2E);
  }
}

__global__ __launch_bounds__(1024, 4) void maf_main(
    const float* __restrict__ x, const float* __restrict__ ctx,
    const float* __restrict__ b1, const float* __restrict__ b2,
    const unsigned short* __restrict__ ws, float* __restrict__ out)
{
  // LDS: 2560 + 139264 = 141824 B -> 1 block/CU (4 waves/EU, 128-reg cap)
  __shared__ __align__(16) unsigned short ybf[32][40];  // y bf16 [s][d]
  __shared__ __align__(16) float Ppw[16][32][68];       // per-wave P partials [w][s][c]

  const unsigned short* W1mT  = ws;            // [1024][32]
  const unsigned short* W2mTp = ws + 32768;    // [64][1024] (k-permuted)
  const unsigned short* WcT   = ws + 98304;    // [1024][64]

  const int tid  = threadIdx.x;
  const int lane = tid & 63;
  const int w    = tid >> 6;        // wave 0..15: owns h-chunk [64w, 64w+64)
  const int l15  = lane & 15;
  const int lk   = lane >> 4;       // 0..3
  const int s0   = blockIdx.x * 32;

  // zero y
  if (tid < 640) reinterpret_cast<unsigned int*>(&ybf[0][0])[tid] = 0u;

  // ---- ctx B-fragments from global (f32 -> bf16 via cvt_pk) ----
  short8 cf[2][2];
#pragma unroll
  for (int sh = 0; sh < 2; ++sh)
#pragma unroll
    for (int kc = 0; kc < 2; ++kc) {
      const float* cp = ctx + (size_t)(s0 + sh * 16 + l15) * 64 + kc * 32 + lk * 8;
      f32x4 a = *reinterpret_cast<const f32x4*>(cp);
      f32x4 b = *reinterpret_cast<const f32x4*>(cp + 4);
      union { short8 s; unsigned int u[4]; } t;
      t.u[0] = cvt_pk_bf16(a[0], a[1]);
      t.u[1] = cvt_pk_bf16(a[2], a[3]);
      t.u[2] = cvt_pk_bf16(b[0], b[1]);
      t.u[3] = cvt_pk_bf16(b[2], b[3]);
      cf[sh][kc] = t.s;
    }

  // ---- WcH^T + b1 (both pre-scaled) for this wave's 64 h-rows; f32 (32 regs) ----
  f32x4 wch[2][4];
#pragma unroll
  for (int j = 0; j < 4; ++j) {
    int h0 = w * 64 + j * 16;
    f32x4 binit = *reinterpret_cast<const f32x4*>(b1 + h0 + 4 * lk);
    binit *= K2LOG2E;
#pragma unroll
    for (int sh = 0; sh < 2; ++sh) {
      f32x4 acc = binit;
#pragma unroll
      for (int kc = 0; kc < 2; ++kc) {
        short8 af = *reinterpret_cast<const short8*>(WcT + (size_t)(h0 + l15) * 64 + kc * 32 + lk * 8);
        acc = __builtin_amdgcn_mfma_f32_16x16x32_bf16(af, cf[sh][kc], acc, 0, 0, 0);
      }
      wch[sh][j] = acc;
    }
  }

  // ---- W1 A-fragments, register-resident (16 regs) ----
  short8 w1f[4];
#pragma unroll
  for (int j = 0; j < 4; ++j)
    w1f[j] = *reinterpret_cast<const short8*>(W1mT + (size_t)(w * 64 + j * 16 + l15) * 32 + lk * 8);

  // ---- W2 B-fragments for own h-chunk, all 64 c (32 regs): w2f[ct][m] ----
  short8 w2f[4][2];
#pragma unroll
  for (int ct = 0; ct < 4; ++ct)
#pragma unroll
    for (int m = 0; m < 2; ++m)
      w2f[ct][m] = *reinterpret_cast<const short8*>(
          W2mTp + (size_t)(16 * ct + l15) * 1024 + w * 64 + m * 32 + lk * 8);

  // ---- epilogue role: thread -> (sample se, dim de) ----
  const int se = tid >> 5, de = tid & 31;
  const float xv  = x[(size_t)(s0 + se) * 32 + de];
  const float b2e = b2[2 * de];
  const float b2o = b2[2 * de + 1] * KLOG2E;     // log2 domain
  float ls_last = 0.f;

  __syncthreads();

#pragma unroll 1
  for (int step = 0; step < 32; ++step) {
    // ---- GEMM1 + tanh, all in registers; pa[sh][j] = packed bf16 hid frags ----
    short8 yb0 = *reinterpret_cast<const short8*>(&ybf[l15][lk * 8]);
    short8 yb1 = *reinterpret_cast<const short8*>(&ybf[16 + l15][lk * 8]);
    unsigned int pa[2][4][2];
#pragma unroll
    for (int j = 0; j < 4; ++j) {
      f32x4 c0 = __builtin_amdgcn_mfma_f32_16x16x32_bf16(w1f[j], yb0, wch[0][j], 0, 0, 0);
      f32x4 c1 = __builtin_amdgcn_mfma_f32_16x16x32_bf16(w1f[j], yb1, wch[1][j], 0, 0, 0);
      pa[0][j][0] = cvt_pk_bf16(tanh_pre(c0[0]), tanh_pre(c0[1]));
      pa[0][j][1] = cvt_pk_bf16(tanh_pre(c0[2]), tanh_pre(c0[3]));
      pa[1][j][0] = cvt_pk_bf16(tanh_pre(c1[0]), tanh_pre(c1[1]));
      pa[1][j][1] = cvt_pk_bf16(tanh_pre(c1[2]), tanh_pre(c1[3]));
    }

    // ---- GEMM2 over own h-chunk from registers; sh-outer so A-frags built once ----
#pragma unroll
    for (int sh = 0; sh < 2; ++sh) {
      union { unsigned int u[4]; short8 s; } a0, a1;
      a0.u[0] = pa[sh][0][0]; a0.u[1] = pa[sh][0][1];
      a0.u[2] = pa[sh][1][0]; a0.u[3] = pa[sh][1][1];
      a1.u[0] = pa[sh][2][0]; a1.u[1] = pa[sh][2][1];
      a1.u[2] = pa[sh][3][0]; a1.u[3] = pa[sh][3][1];
#pragma unroll
      for (int ct = 0; ct < 4; ++ct) {
        f32x4 acc = {0.f, 0.f, 0.f, 0.f};
        acc = __builtin_amdgcn_mfma_f32_16x16x32_bf16(a0.s, w2f[ct][0], acc, 0, 0, 0);
        acc = __builtin_amdgcn_mfma_f32_16x16x32_bf16(a1.s, w2f[ct][1], acc, 0, 0, 0);
#pragma unroll
        for (int r = 0; r < 4; ++r)
          Ppw[w][16 * sh + 4 * lk + r][16 * ct + l15] = acc[r];
      }
    }
    __syncthreads();

    // ---- epilogue: thread (se, de): f32x2 tree-reduce 16 slices ----
    {
      f32x2 t0, t1, t2, t3, t4, t5, t6, t7;
      t0 = *reinterpret_cast<const f32x2*>(&Ppw[0][se][2 * de])
         + *reinterpret_cast<const f32x2*>(&Ppw[1][se][2 * de]);
      t1 = *reinterpret_cast<const f32x2*>(&Ppw[2][se][2 * de])
         + *reinterpret_cast<const f32x2*>(&Ppw[3][se][2 * de]);
      t2 = *reinterpret_cast<const f32x2*>(&Ppw[4][se][2 * de])
         + *reinterpret_cast<const f32x2*>(&Ppw[5][se][2 * de]);
      t3 = *reinterpret_cast<const f32x2*>(&Ppw[6][se][2 * de])
         + *reinterpret_cast<const f32x2*>(&Ppw[7][se][2 * de]);
      t4 = *reinterpret_cast<const f32x2*>(&Ppw[8][se][2 * de])
         + *reinterpret_cast<const f32x2*>(&Ppw[9][se][2 * de]);
      t5 = *reinterpret_cast<const f32x2*>(&Ppw[10][se][2 * de])
         + *reinterpret_cast<const f32x2*>(&Ppw[11][se][2 * de]);
      t6 = *reinterpret_cast<const f32x2*>(&Ppw[12][se][2 * de])
         + *reinterpret_cast<const f32x2*>(&Ppw[13][se][2 * de]);
      t7 = *reinterpret_cast<const f32x2*>(&Ppw[14][se][2 * de])
         + *reinterpret_cast<const f32x2*>(&Ppw[15][se][2 * de]);
      t0 += t4; t1 += t5; t2 += t6; t3 += t7;
      t0 += t2; t1 += t3;
      t0 += t1;
      float shv = t0[0] + b2e;
      float lsv = t0[1] + b2o;                       // log2 domain
      float yv = fmaf(xv, __builtin_amdgcn_exp2f(lsv), shv);
      ybf[se][de] = f2bf(yv);
      if (step == 31) {
        out[(size_t)(s0 + se) * 32 + de] = yv;
        ls_last = lsv * KLN2;                        // back to natural log
      }
    }
    __syncthreads();
  }

  // ---- log_det: reduce ls over de within each 32-lane group ----
  float v = ls_last;
  v += __shfl_xor(v, 1);
  v += __shfl_xor(v, 2);
  v += __shfl_xor(v, 4);
  v += __shfl_xor(v, 8);
  v += __shfl_xor(v, 16);
  if (de == 0) out[(size_t)NS * 32 + s0 + se] = v;
}

extern "C" void kernel_launch(void* const* d_in, const int* in_sizes, int n_in,
                              void* d_out, int out_size, void* d_ws, size_t ws_size,
                              hipStream_t stream) {
  (void)in_sizes; (void)n_in; (void)out_size; (void)ws_size;
  const float* x   = (const float*)d_in[0];
  const float* ctx = (const float*)d_in[1];
  const float* W1  = (const float*)d_in[2];
  const float* b1  = (const float*)d_in[3];
  const float* Wc  = (const float*)d_in[4];
  const float* W2  = (const float*)d_in[5];
  const float* b2  = (const float*)d_in[6];
  unsigned short* ws = (unsigned short*)d_ws;
  float* out = (float*)d_out;

  maf_prep<<<640, 256, 0, stream>>>(W1, Wc, W2, ws);
  maf_main<<<2048, 1024, 0, stream>>>(x, ctx, b1, b2, ws, out);
}